// Round 1
// baseline (1065.227 us; speedup 1.0000x reference)
//
#include <hip/hip_runtime.h>
#include <hip/hip_bf16.h>
#include <math.h>

#define N 8192
#define D 128
#define CAP 512   // max stored neighbors per row (true max deg ~165+13*sigma; 27 sigma margin)

// ---------------------------------------------------------------------------
// Build padded adjacency lists from the dense int32 mask.
// One block per row; ~2% density -> ~165 neighbors/row. Order within a row is
// nondeterministic (atomicAdd on LDS counter) -> fp32 sum reorder only, fine
// under the 9.9e-2 absmax threshold.
// ---------------------------------------------------------------------------
__global__ __launch_bounds__(256) void build_adj(const int* __restrict__ mask,
                                                 unsigned short* __restrict__ nbr,
                                                 int* __restrict__ deg) {
    const int i = blockIdx.x;
    __shared__ int cnt;
    if (threadIdx.x == 0) cnt = 0;
    __syncthreads();
    const int* row = mask + (size_t)i * N;
    for (int j = threadIdx.x; j < N; j += 256) {
        if (row[j] != 0) {
            int p = atomicAdd(&cnt, 1);
            if (p < CAP) nbr[(size_t)i * CAP + p] = (unsigned short)j;
        }
    }
    __syncthreads();
    if (threadIdx.x == 0) deg[i] = (cnt > CAP) ? CAP : cnt;
}

// ---------------------------------------------------------------------------
// C[i][j] = sum_k A[i][k] * W[k][j] + bias[j]    A:[N,128] W:[128,128] C:[N,128]
// Block = 128 threads (one per output col), 16 rows per block.
// A-tile in LDS (broadcast float4 reads); W column loads coalesced across j.
// ---------------------------------------------------------------------------
__global__ __launch_bounds__(128) void gemm_bias(const float* __restrict__ A,
                                                 const float* __restrict__ W,
                                                 const float* __restrict__ bias,
                                                 float* __restrict__ C) {
    __shared__ float As[16][D];
    const int j  = threadIdx.x;
    const int i0 = blockIdx.x * 16;

    #pragma unroll
    for (int r = 0; r < 16; ++r)
        As[r][j] = A[(size_t)(i0 + r) * D + j];
    __syncthreads();

    float acc[16];
    const float bj = bias[j];
    #pragma unroll
    for (int r = 0; r < 16; ++r) acc[r] = bj;

    for (int k = 0; k < D; k += 4) {
        const float w0 = W[(k + 0) * D + j];
        const float w1 = W[(k + 1) * D + j];
        const float w2 = W[(k + 2) * D + j];
        const float w3 = W[(k + 3) * D + j];
        #pragma unroll
        for (int r = 0; r < 16; ++r) {
            float4 a4 = *(const float4*)&As[r][k];
            acc[r] += a4.x * w0 + a4.y * w1 + a4.z * w2 + a4.w * w3;
        }
    }
    #pragma unroll
    for (int r = 0; r < 16; ++r)
        C[(size_t)(i0 + r) * D + j] = acc[r];
}

// ---------------------------------------------------------------------------
// Sparse masked attention: one block (256 thr = 4 waves) per query row i.
//   s_e = dot(Q_i, K_{j_e}) * scale   (wave per neighbor, shfl_xor reduce)
//   softmax over the ~165 valid entries
//   h_i = sum_e p_e * V_{j_e}         (2-way split over e, 128 dims coalesced)
// ---------------------------------------------------------------------------
__global__ __launch_bounds__(256) void attn_sparse(const float* __restrict__ Q,
                                                   const float* __restrict__ K,
                                                   const float* __restrict__ V,
                                                   const unsigned short* __restrict__ nbr,
                                                   const int* __restrict__ deg,
                                                   float* __restrict__ Hout) {
    const int i   = blockIdx.x;
    const int tid = threadIdx.x;
    const int wave = tid >> 6;
    const int lane = tid & 63;

    __shared__ float Qs[D];
    __shared__ float s[CAP];
    __shared__ int   jl[CAP];
    __shared__ float red[256];
    __shared__ float m_sh, inv_sh;

    if (tid < D) Qs[tid] = Q[(size_t)i * D + tid];
    __syncthreads();

    const int dg = deg[i];
    const float q0 = Qs[2 * lane];
    const float q1 = Qs[2 * lane + 1];
    const float scale = 0.088388347648318447f;  // 1/sqrt(128)

    // phase 2: scores for valid neighbors
    for (int e = wave; e < dg; e += 4) {
        const int j = (int)nbr[(size_t)i * CAP + e];
        const float2 k2 = *(const float2*)(K + (size_t)j * D + 2 * lane);
        float partial = k2.x * q0 + k2.y * q1;
        #pragma unroll
        for (int off = 32; off > 0; off >>= 1)
            partial += __shfl_xor(partial, off);
        if (lane == 0) { s[e] = partial * scale; jl[e] = j; }
    }
    __syncthreads();

    // phase 3: softmax over s[0..dg)
    float lm = -1e30f;
    for (int e = tid; e < dg; e += 256) lm = fmaxf(lm, s[e]);
    red[tid] = lm; __syncthreads();
    for (int st = 128; st > 0; st >>= 1) {
        if (tid < st) red[tid] = fmaxf(red[tid], red[tid + st]);
        __syncthreads();
    }
    if (tid == 0) m_sh = red[0];
    __syncthreads();
    const float m = m_sh;
    __syncthreads();

    float ls = 0.f;
    for (int e = tid; e < dg; e += 256) {
        float p = __expf(s[e] - m);
        s[e] = p;
        ls += p;
    }
    red[tid] = ls; __syncthreads();
    for (int st = 128; st > 0; st >>= 1) {
        if (tid < st) red[tid] += red[tid + st];
        __syncthreads();
    }
    if (tid == 0) inv_sh = 1.0f / red[0];
    __syncthreads();
    const float inv = inv_sh;

    // phase 4: weighted sum of V rows (split e-range over 2 thread halves)
    const int half = tid >> 7;
    const int d    = tid & 127;
    float acc = 0.f;
    for (int e = half; e < dg; e += 2) {
        const float p = s[e];
        const int   j = jl[e];
        acc += p * V[(size_t)j * D + d];
    }
    __syncthreads();           // s/red reuse barrier
    red[tid] = acc; __syncthreads();
    if (tid < 128)
        Hout[(size_t)i * D + tid] = (red[tid] + red[tid + 128]) * inv;
}

__global__ __launch_bounds__(256) void copy_f4(const float4* __restrict__ in,
                                               float4* __restrict__ out, int n4) {
    int idx = blockIdx.x * 256 + threadIdx.x;
    if (idx < n4) out[idx] = in[idx];
}

extern "C" void kernel_launch(void* const* d_in, const int* in_sizes, int n_in,
                              void* d_out, int out_size, void* d_ws, size_t ws_size,
                              hipStream_t stream) {
    const float* features = (const float*)d_in[0];
    const int*   mask     = (const int*)d_in[1];
    const float* Wq = (const float*)d_in[2];
    const float* bq = (const float*)d_in[3];
    const float* Wk = (const float*)d_in[4];
    const float* bk = (const float*)d_in[5];
    const float* Wv = (const float*)d_in[6];
    const float* bv = (const float*)d_in[7];
    const float* Wo = (const float*)d_in[8];
    const float* bo = (const float*)d_in[9];
    float* out = (float*)d_out;

    // workspace layout (needs ~25.2 MB)
    char* base = (char*)d_ws;
    unsigned short* nbr = (unsigned short*)base;                       // 8 MB
    int*   deg = (int*)(base + (size_t)N * CAP * 2);                   // 32 KB
    float* Qb  = (float*)(base + (size_t)N * CAP * 2 + N * 4);         // 4 MB
    float* Kb  = Qb + (size_t)N * D;                                   // 4 MB
    float* Vb  = Kb + (size_t)N * D;                                   // 4 MB
    float* tmp = Vb + (size_t)N * D;                                   // 4 MB

    // adjacency from mask (once per call; reused across both layers)
    build_adj<<<N, 256, 0, stream>>>(mask, nbr, deg);

    // output 0 = features
    copy_f4<<<(N * D / 4 + 255) / 256, 256, 0, stream>>>(
        (const float4*)features, (float4*)out, N * D / 4);

    for (int l = 0; l < 2; ++l) {
        const float* hin = (l == 0) ? features : (out + (size_t)N * D);
        float* hout = out + (size_t)(l + 1) * N * D;
        const size_t wo = (size_t)l * D * D;
        const size_t bofs = (size_t)l * D;

        gemm_bias<<<N / 16, 128, 0, stream>>>(hin, Wq + wo, bq + bofs, Qb);
        gemm_bias<<<N / 16, 128, 0, stream>>>(hin, Wk + wo, bk + bofs, Kb);
        gemm_bias<<<N / 16, 128, 0, stream>>>(hin, Wv + wo, bv + bofs, Vb);
        attn_sparse<<<N, 256, 0, stream>>>(Qb, Kb, Vb, nbr, deg, tmp);
        gemm_bias<<<N / 16, 128, 0, stream>>>(tmp, Wo + wo, bo + bofs, hout);
    }
}

// Round 2
// 820.549 us; speedup vs baseline: 1.2982x; 1.2982x over previous
//
#include <hip/hip_runtime.h>
#include <hip/hip_bf16.h>
#include <math.h>

#define N 8192
#define D 128
#define CAP 512   // max stored neighbors per row (true max deg ~165+13*sigma)

// ---------------------------------------------------------------------------
// Build padded adjacency lists from the dense int32 mask. int4-vectorized.
// ---------------------------------------------------------------------------
__global__ __launch_bounds__(256) void build_adj(const int* __restrict__ mask,
                                                 unsigned short* __restrict__ nbr,
                                                 int* __restrict__ deg) {
    const int i = blockIdx.x;
    __shared__ int cnt;
    if (threadIdx.x == 0) cnt = 0;
    __syncthreads();
    const int4* row = (const int4*)(mask + (size_t)i * N);
    for (int c = threadIdx.x; c < N / 4; c += 256) {   // 8 iterations
        int4 m4 = row[c];
        int base = 4 * c;
        if (m4.x) { int p = atomicAdd(&cnt, 1); if (p < CAP) nbr[(size_t)i * CAP + p] = (unsigned short)(base); }
        if (m4.y) { int p = atomicAdd(&cnt, 1); if (p < CAP) nbr[(size_t)i * CAP + p] = (unsigned short)(base + 1); }
        if (m4.z) { int p = atomicAdd(&cnt, 1); if (p < CAP) nbr[(size_t)i * CAP + p] = (unsigned short)(base + 2); }
        if (m4.w) { int p = atomicAdd(&cnt, 1); if (p < CAP) nbr[(size_t)i * CAP + p] = (unsigned short)(base + 3); }
    }
    __syncthreads();
    if (threadIdx.x == 0) deg[i] = (cnt > CAP) ? CAP : cnt;
}

// ---------------------------------------------------------------------------
// C[i][j] = sum_k A[i][k]*W[k][j] + bias[j].  A:[N,128] W:[128,128] C:[N,128]
// Block = 256 threads, 8 rows x 128 cols; thread = 1 row x 4 cols (float4 acc).
// 1024 blocks x 4 waves = 16 waves/CU grid-wide (vs 4 in R1).
// A broadcast from LDS (2 addrs/wave = free); W row loads coalesced, L2-hot.
// ---------------------------------------------------------------------------
__global__ __launch_bounds__(256) void gemm_bias(const float* __restrict__ A,
                                                 const float* __restrict__ W,
                                                 const float* __restrict__ bias,
                                                 float* __restrict__ C) {
    __shared__ float As[8][D];
    const int tid = threadIdx.x;
    const int r   = tid >> 5;        // 0..7
    const int jg  = tid & 31;        // cols 4*jg .. 4*jg+3
    const int i0  = blockIdx.x * 8;

    // stage 8 rows of A (contiguous 4 KB) with one float4 per thread
    ((float4*)&As[0][0])[tid] = ((const float4*)(A + (size_t)i0 * D))[tid];
    __syncthreads();

    float4 acc = *(const float4*)(bias + 4 * jg);

    #pragma unroll 8
    for (int k4 = 0; k4 < 32; ++k4) {
        const float4 a4 = *(const float4*)&As[r][4 * k4];
        const float* wb = W + (size_t)(4 * k4) * D + 4 * jg;
        const float4 w0 = *(const float4*)(wb);
        const float4 w1 = *(const float4*)(wb + D);
        const float4 w2 = *(const float4*)(wb + 2 * D);
        const float4 w3 = *(const float4*)(wb + 3 * D);
        acc.x += a4.x * w0.x + a4.y * w1.x + a4.z * w2.x + a4.w * w3.x;
        acc.y += a4.x * w0.y + a4.y * w1.y + a4.z * w2.y + a4.w * w3.y;
        acc.z += a4.x * w0.z + a4.y * w1.z + a4.z * w2.z + a4.w * w3.z;
        acc.w += a4.x * w0.w + a4.y * w1.w + a4.z * w2.w + a4.w * w3.w;
    }
    *(float4*)(C + (size_t)(i0 + r) * D + 4 * jg) = acc;
}

// ---------------------------------------------------------------------------
// Sparse masked attention: one block (256 thr) per query row i.
// Phase 2: thread-per-neighbor FULL dot product (no cross-lane reduce).
// Phase 3: single-wave butterfly softmax (2 block barriers total).
// Phase 4: 4-way e-split, float2 V loads, LDS combine.
// ---------------------------------------------------------------------------
__global__ __launch_bounds__(256) void attn_sparse(const float* __restrict__ Q,
                                                   const float* __restrict__ K,
                                                   const float* __restrict__ V,
                                                   const unsigned short* __restrict__ nbr,
                                                   const int* __restrict__ deg,
                                                   float* __restrict__ Hout) {
    const int i    = blockIdx.x;
    const int tid  = threadIdx.x;
    const int wave = tid >> 6;
    const int lane = tid & 63;

    __shared__ float          Qs[D];
    __shared__ float          s[CAP];
    __shared__ unsigned short jls[CAP];
    __shared__ float          accx[256];
    __shared__ float          accy[256];
    __shared__ float          inv_sh;

    if (tid < D) Qs[tid] = Q[(size_t)i * D + tid];
    const int dg = deg[i];
    for (int e = tid; e < dg; e += 256) jls[e] = nbr[(size_t)i * CAP + e];
    __syncthreads();

    const float scale = 0.088388347648318447f;  // 1/sqrt(128)

    // phase 2: independent full dots, one neighbor per thread
    for (int e = tid; e < dg; e += 256) {
        const float4* kr = (const float4*)(K + (size_t)jls[e] * D);
        float dot = 0.f;
        #pragma unroll 8
        for (int k = 0; k < 32; ++k) {
            const float4 kv = kr[k];
            const float4 qv = *(const float4*)&Qs[4 * k];
            dot += kv.x * qv.x + kv.y * qv.y + kv.z * qv.z + kv.w * qv.w;
        }
        s[e] = dot * scale;
    }
    __syncthreads();

    // phase 3: softmax on wave 0 only (butterfly shfl over 64 lanes)
    if (wave == 0) {
        float lm = -1e30f;
        for (int e = lane; e < dg; e += 64) lm = fmaxf(lm, s[e]);
        #pragma unroll
        for (int off = 32; off > 0; off >>= 1)
            lm = fmaxf(lm, __shfl_xor(lm, off));
        float ls = 0.f;
        for (int e = lane; e < dg; e += 64) {
            const float p = __expf(s[e] - lm);
            s[e] = p;
            ls += p;
        }
        #pragma unroll
        for (int off = 32; off > 0; off >>= 1)
            ls += __shfl_xor(ls, off);
        if (lane == 0) inv_sh = 1.0f / ls;
    }
    __syncthreads();

    // phase 4: weighted V sum; quarter q handles e = q, q+4, ... ; float2 dims
    float ax = 0.f, ay = 0.f;
    for (int e = wave; e < dg; e += 4) {
        const float  p  = s[e];
        const float2 v2 = *(const float2*)(V + (size_t)jls[e] * D + 2 * lane);
        ax += p * v2.x;
        ay += p * v2.y;
    }
    accx[tid] = ax;
    accy[tid] = ay;
    __syncthreads();
    if (tid < 64) {
        const float inv = inv_sh;
        const float sx = (accx[tid] + accx[tid + 64] + accx[tid + 128] + accx[tid + 192]) * inv;
        const float sy = (accy[tid] + accy[tid + 64] + accy[tid + 128] + accy[tid + 192]) * inv;
        float2 o; o.x = sx; o.y = sy;
        *(float2*)(Hout + (size_t)i * D + 2 * tid) = o;
    }
}

__global__ __launch_bounds__(256) void copy_f4(const float4* __restrict__ in,
                                               float4* __restrict__ out, int n4) {
    int idx = blockIdx.x * 256 + threadIdx.x;
    if (idx < n4) out[idx] = in[idx];
}

extern "C" void kernel_launch(void* const* d_in, const int* in_sizes, int n_in,
                              void* d_out, int out_size, void* d_ws, size_t ws_size,
                              hipStream_t stream) {
    const float* features = (const float*)d_in[0];
    const int*   mask     = (const int*)d_in[1];
    const float* Wq = (const float*)d_in[2];
    const float* bq = (const float*)d_in[3];
    const float* Wk = (const float*)d_in[4];
    const float* bk = (const float*)d_in[5];
    const float* Wv = (const float*)d_in[6];
    const float* bv = (const float*)d_in[7];
    const float* Wo = (const float*)d_in[8];
    const float* bo = (const float*)d_in[9];
    float* out = (float*)d_out;

    // workspace layout (~25.2 MB)
    char* base = (char*)d_ws;
    unsigned short* nbr = (unsigned short*)base;                       // 8 MB
    int*   deg = (int*)(base + (size_t)N * CAP * 2);                   // 32 KB
    float* Qb  = (float*)(base + (size_t)N * CAP * 2 + N * 4);         // 4 MB
    float* Kb  = Qb + (size_t)N * D;                                   // 4 MB
    float* Vb  = Kb + (size_t)N * D;                                   // 4 MB
    float* tmp = Vb + (size_t)N * D;                                   // 4 MB

    build_adj<<<N, 256, 0, stream>>>(mask, nbr, deg);

    copy_f4<<<(N * D / 4 + 255) / 256, 256, 0, stream>>>(
        (const float4*)features, (float4*)out, N * D / 4);

    for (int l = 0; l < 2; ++l) {
        const float* hin = (l == 0) ? features : (out + (size_t)N * D);
        float* hout = out + (size_t)(l + 1) * N * D;
        const size_t wo = (size_t)l * D * D;
        const size_t bofs = (size_t)l * D;

        gemm_bias<<<N / 8, 256, 0, stream>>>(hin, Wq + wo, bq + bofs, Qb);
        gemm_bias<<<N / 8, 256, 0, stream>>>(hin, Wk + wo, bk + bofs, Kb);
        gemm_bias<<<N / 8, 256, 0, stream>>>(hin, Wv + wo, bv + bofs, Vb);
        attn_sparse<<<N, 256, 0, stream>>>(Qb, Kb, Vb, nbr, deg, tmp);
        gemm_bias<<<N / 8, 256, 0, stream>>>(tmp, Wo + wo, bo + bofs, hout);
    }
}

// Round 3
// 768.284 us; speedup vs baseline: 1.3865x; 1.0680x over previous
//
#include <hip/hip_runtime.h>
#include <hip/hip_bf16.h>
#include <hip/hip_fp16.h>
#include <math.h>

#define N 8192
#define D 128
#define CAP 512   // max stored neighbors per row (true max deg ~165+13*sigma)

typedef _Float16 f16x2 __attribute__((ext_vector_type(2)));
typedef _Float16 f16x4 __attribute__((ext_vector_type(4)));
typedef _Float16 f16x8 __attribute__((ext_vector_type(8)));

__device__ __forceinline__ float dot2(f16x2 a, f16x2 b, float c) {
#if __has_builtin(__builtin_amdgcn_fdot2)
    return __builtin_amdgcn_fdot2(a, b, c, false);
#else
    return c + (float)a[0] * (float)b[0] + (float)a[1] * (float)b[1];
#endif
}

// ---------------------------------------------------------------------------
// Build padded adjacency lists from the dense int32 mask. int4-vectorized.
// HBM-bound floor: 256 MB read.
// ---------------------------------------------------------------------------
__global__ __launch_bounds__(256) void build_adj(const int* __restrict__ mask,
                                                 unsigned short* __restrict__ nbr,
                                                 int* __restrict__ deg) {
    const int i = blockIdx.x;
    __shared__ int cnt;
    if (threadIdx.x == 0) cnt = 0;
    __syncthreads();
    const int4* row = (const int4*)(mask + (size_t)i * N);
    for (int c = threadIdx.x; c < N / 4; c += 256) {
        int4 m4 = row[c];
        int base = 4 * c;
        if (m4.x) { int p = atomicAdd(&cnt, 1); if (p < CAP) nbr[(size_t)i * CAP + p] = (unsigned short)(base); }
        if (m4.y) { int p = atomicAdd(&cnt, 1); if (p < CAP) nbr[(size_t)i * CAP + p] = (unsigned short)(base + 1); }
        if (m4.z) { int p = atomicAdd(&cnt, 1); if (p < CAP) nbr[(size_t)i * CAP + p] = (unsigned short)(base + 2); }
        if (m4.w) { int p = atomicAdd(&cnt, 1); if (p < CAP) nbr[(size_t)i * CAP + p] = (unsigned short)(base + 3); }
    }
    __syncthreads();
    if (threadIdx.x == 0) deg[i] = (cnt > CAP) ? CAP : cnt;
}

// ---------------------------------------------------------------------------
// Fused Q/K/V projection: A[8 rows] staged once in LDS, 3 GEMMs, f16 outputs.
// Block = 256 thr, thread = 1 row x 4 cols per matrix.
// ---------------------------------------------------------------------------
__global__ __launch_bounds__(256) void qkv_gemm(const float* __restrict__ A,
                                                const float* __restrict__ Wq, const float* __restrict__ bq,
                                                const float* __restrict__ Wk, const float* __restrict__ bk,
                                                const float* __restrict__ Wv, const float* __restrict__ bv,
                                                __half* __restrict__ Qo, __half* __restrict__ Ko,
                                                __half* __restrict__ Vo) {
    __shared__ float As[8][D];
    const int tid = threadIdx.x;
    const int r   = tid >> 5;
    const int jg  = tid & 31;
    const int i0  = blockIdx.x * 8;

    ((float4*)&As[0][0])[tid] = ((const float4*)(A + (size_t)i0 * D))[tid];
    __syncthreads();

    const float* Ws[3] = {Wq, Wk, Wv};
    const float* bs[3] = {bq, bk, bv};
    __half* Os[3] = {Qo, Ko, Vo};

    #pragma unroll
    for (int m = 0; m < 3; ++m) {
        float4 acc = *(const float4*)(bs[m] + 4 * jg);
        const float* W = Ws[m];
        #pragma unroll 8
        for (int k4 = 0; k4 < 32; ++k4) {
            const float4 a4 = *(const float4*)&As[r][4 * k4];
            const float* wb = W + (size_t)(4 * k4) * D + 4 * jg;
            const float4 w0 = *(const float4*)(wb);
            const float4 w1 = *(const float4*)(wb + D);
            const float4 w2 = *(const float4*)(wb + 2 * D);
            const float4 w3 = *(const float4*)(wb + 3 * D);
            acc.x += a4.x * w0.x + a4.y * w1.x + a4.z * w2.x + a4.w * w3.x;
            acc.y += a4.x * w0.y + a4.y * w1.y + a4.z * w2.y + a4.w * w3.y;
            acc.z += a4.x * w0.z + a4.y * w1.z + a4.z * w2.z + a4.w * w3.z;
            acc.w += a4.x * w0.w + a4.y * w1.w + a4.z * w2.w + a4.w * w3.w;
        }
        f16x4 h;
        h[0] = (_Float16)acc.x; h[1] = (_Float16)acc.y;
        h[2] = (_Float16)acc.z; h[3] = (_Float16)acc.w;
        *(f16x4*)(Os[m] + (size_t)(i0 + r) * D + 4 * jg) = h;
    }
}

// ---------------------------------------------------------------------------
// Output projection (fp32 in/out), R2 structure.
// ---------------------------------------------------------------------------
__global__ __launch_bounds__(256) void gemm_bias(const float* __restrict__ A,
                                                 const float* __restrict__ W,
                                                 const float* __restrict__ bias,
                                                 float* __restrict__ C) {
    __shared__ float As[8][D];
    const int tid = threadIdx.x;
    const int r   = tid >> 5;
    const int jg  = tid & 31;
    const int i0  = blockIdx.x * 8;

    ((float4*)&As[0][0])[tid] = ((const float4*)(A + (size_t)i0 * D))[tid];
    __syncthreads();

    float4 acc = *(const float4*)(bias + 4 * jg);
    #pragma unroll 8
    for (int k4 = 0; k4 < 32; ++k4) {
        const float4 a4 = *(const float4*)&As[r][4 * k4];
        const float* wb = W + (size_t)(4 * k4) * D + 4 * jg;
        const float4 w0 = *(const float4*)(wb);
        const float4 w1 = *(const float4*)(wb + D);
        const float4 w2 = *(const float4*)(wb + 2 * D);
        const float4 w3 = *(const float4*)(wb + 3 * D);
        acc.x += a4.x * w0.x + a4.y * w1.x + a4.z * w2.x + a4.w * w3.x;
        acc.y += a4.x * w0.y + a4.y * w1.y + a4.z * w2.y + a4.w * w3.y;
        acc.z += a4.x * w0.z + a4.y * w1.z + a4.z * w2.z + a4.w * w3.z;
        acc.w += a4.x * w0.w + a4.y * w1.w + a4.z * w2.w + a4.w * w3.w;
    }
    *(float4*)(C + (size_t)(i0 + r) * D + 4 * jg) = acc;
}

// ---------------------------------------------------------------------------
// Sparse masked attention, f16 Q/K/V. One block (256 thr) per query row.
// Phase 2: thread-per-neighbor dot via v_dot2_f32_f16 (16 x 16B loads/row).
// Phase 3: single-wave butterfly softmax.
// Phase 4: 8-way e-split; 32 lanes x 8B = one V row (256 B) contiguous.
// ---------------------------------------------------------------------------
__global__ __launch_bounds__(256) void attn_sparse(const __half* __restrict__ Q,
                                                   const __half* __restrict__ K,
                                                   const __half* __restrict__ V,
                                                   const unsigned short* __restrict__ nbr,
                                                   const int* __restrict__ deg,
                                                   float* __restrict__ Hout) {
    const int i    = blockIdx.x;
    const int tid  = threadIdx.x;
    const int wave = tid >> 6;
    const int lane = tid & 63;

    __shared__ f16x8          Qs8[16];     // 256 B
    __shared__ float          s[CAP];
    __shared__ unsigned short jls[CAP];
    __shared__ float4         red4[256];   // 4 KB
    __shared__ float          inv_sh;

    if (tid < 16) Qs8[tid] = ((const f16x8*)(Q + (size_t)i * D))[tid];
    const int dg = deg[i];
    for (int e = tid; e < dg; e += 256) jls[e] = nbr[(size_t)i * CAP + e];
    __syncthreads();

    const float scale = 0.088388347648318447f;  // 1/sqrt(128)

    // phase 2: independent full dots, one neighbor per thread
    for (int e = tid; e < dg; e += 256) {
        const f16x8* kr = (const f16x8*)(K + (size_t)jls[e] * D);
        float dot = 0.f;
        #pragma unroll
        for (int k = 0; k < 16; ++k) {
            const f16x8 kv = kr[k];
            const f16x8 qv = Qs8[k];
            dot = dot2(__builtin_shufflevector(kv, kv, 0, 1),
                       __builtin_shufflevector(qv, qv, 0, 1), dot);
            dot = dot2(__builtin_shufflevector(kv, kv, 2, 3),
                       __builtin_shufflevector(qv, qv, 2, 3), dot);
            dot = dot2(__builtin_shufflevector(kv, kv, 4, 5),
                       __builtin_shufflevector(qv, qv, 4, 5), dot);
            dot = dot2(__builtin_shufflevector(kv, kv, 6, 7),
                       __builtin_shufflevector(qv, qv, 6, 7), dot);
        }
        s[e] = dot * scale;
    }
    __syncthreads();

    // phase 3: softmax on wave 0 (butterfly over 64 lanes)
    if (wave == 0) {
        float lm = -1e30f;
        for (int e = lane; e < dg; e += 64) lm = fmaxf(lm, s[e]);
        #pragma unroll
        for (int off = 32; off > 0; off >>= 1)
            lm = fmaxf(lm, __shfl_xor(lm, off));
        float ls = 0.f;
        for (int e = lane; e < dg; e += 64) {
            const float p = __expf(s[e] - lm);
            s[e] = p;
            ls += p;
        }
        #pragma unroll
        for (int off = 32; off > 0; off >>= 1)
            ls += __shfl_xor(ls, off);
        if (lane == 0) inv_sh = 1.0f / ls;
    }
    __syncthreads();

    // phase 4: weighted V sum. thread = (e-slice tid>>5, dim-group tid&31)
    const int dq = tid & 31;
    const int e0 = tid >> 5;
    float4 acc = {0.f, 0.f, 0.f, 0.f};
    for (int e = e0; e < dg; e += 8) {
        const float p = s[e];
        const f16x4 v4 = ((const f16x4*)(V + (size_t)jls[e] * D))[dq];
        acc.x += p * (float)v4[0];
        acc.y += p * (float)v4[1];
        acc.z += p * (float)v4[2];
        acc.w += p * (float)v4[3];
    }
    red4[tid] = acc;
    __syncthreads();
    if (tid < 32) {
        const float inv = inv_sh;
        float4 sum = red4[tid];
        #pragma unroll
        for (int q = 1; q < 8; ++q) {
            const float4 t = red4[tid + 32 * q];
            sum.x += t.x; sum.y += t.y; sum.z += t.z; sum.w += t.w;
        }
        sum.x *= inv; sum.y *= inv; sum.z *= inv; sum.w *= inv;
        *(float4*)(Hout + (size_t)i * D + 4 * tid) = sum;
    }
}

__global__ __launch_bounds__(256) void copy_f4(const float4* __restrict__ in,
                                               float4* __restrict__ out, int n4) {
    int idx = blockIdx.x * 256 + threadIdx.x;
    if (idx < n4) out[idx] = in[idx];
}

extern "C" void kernel_launch(void* const* d_in, const int* in_sizes, int n_in,
                              void* d_out, int out_size, void* d_ws, size_t ws_size,
                              hipStream_t stream) {
    const float* features = (const float*)d_in[0];
    const int*   mask     = (const int*)d_in[1];
    const float* Wq = (const float*)d_in[2];
    const float* bq = (const float*)d_in[3];
    const float* Wk = (const float*)d_in[4];
    const float* bk = (const float*)d_in[5];
    const float* Wv = (const float*)d_in[6];
    const float* bv = (const float*)d_in[7];
    const float* Wo = (const float*)d_in[8];
    const float* bo = (const float*)d_in[9];
    float* out = (float*)d_out;

    // workspace layout (~18.5 MB)
    char* base = (char*)d_ws;
    unsigned short* nbr = (unsigned short*)base;                        // 8 MB
    int*    deg  = (int*)(base + (size_t)N * CAP * 2);                  // 32 KB
    __half* Qb16 = (__half*)(base + (size_t)N * CAP * 2 + N * 4);       // 2 MB
    __half* Kb16 = Qb16 + (size_t)N * D;                                // 2 MB
    __half* Vb16 = Kb16 + (size_t)N * D;                                // 2 MB
    float*  tmp  = (float*)(Vb16 + (size_t)N * D);                      // 4 MB

    build_adj<<<N, 256, 0, stream>>>(mask, nbr, deg);

    copy_f4<<<(N * D / 4 + 255) / 256, 256, 0, stream>>>(
        (const float4*)features, (float4*)out, N * D / 4);

    for (int l = 0; l < 2; ++l) {
        const float* hin = (l == 0) ? features : (out + (size_t)N * D);
        float* hout = out + (size_t)(l + 1) * N * D;
        const size_t wo = (size_t)l * D * D;
        const size_t bofs = (size_t)l * D;

        qkv_gemm<<<N / 8, 256, 0, stream>>>(hin, Wq + wo, bq + bofs,
                                            Wk + wo, bk + bofs,
                                            Wv + wo, bv + bofs,
                                            Qb16, Kb16, Vb16);
        attn_sparse<<<N, 256, 0, stream>>>(Qb16, Kb16, Vb16, nbr, deg, tmp);
        gemm_bias<<<N / 8, 256, 0, stream>>>(tmp, Wo + wo, bo + bofs, hout);
    }
}

// Round 4
// 615.413 us; speedup vs baseline: 1.7309x; 1.2484x over previous
//
#include <hip/hip_runtime.h>
#include <hip/hip_bf16.h>
#include <hip/hip_fp16.h>
#include <math.h>

#define N 8192
#define D 128
#define CAP 512   // max stored neighbors per row (true max deg ~165+13*sigma)

typedef _Float16 f16x2 __attribute__((ext_vector_type(2)));
typedef _Float16 f16x4 __attribute__((ext_vector_type(4)));
typedef _Float16 f16x8 __attribute__((ext_vector_type(8)));

__device__ __forceinline__ float dot2(f16x2 a, f16x2 b, float c) {
#if __has_builtin(__builtin_amdgcn_fdot2)
    return __builtin_amdgcn_fdot2(a, b, c, false);
#else
    return c + (float)a[0] * (float)b[0] + (float)a[1] * (float)b[1];
#endif
}

__device__ __forceinline__ float dot8(f16x8 a, f16x8 b, float c) {
    c = dot2(__builtin_shufflevector(a, a, 0, 1), __builtin_shufflevector(b, b, 0, 1), c);
    c = dot2(__builtin_shufflevector(a, a, 2, 3), __builtin_shufflevector(b, b, 2, 3), c);
    c = dot2(__builtin_shufflevector(a, a, 4, 5), __builtin_shufflevector(b, b, 4, 5), c);
    c = dot2(__builtin_shufflevector(a, a, 6, 7), __builtin_shufflevector(b, b, 6, 7), c);
    return c;
}

// ---------------------------------------------------------------------------
// Adjacency build from dense int32 mask. 256 MB HBM read = ~45 us floor.
// ---------------------------------------------------------------------------
__global__ __launch_bounds__(256) void build_adj(const int* __restrict__ mask,
                                                 unsigned short* __restrict__ nbr,
                                                 int* __restrict__ deg) {
    const int i = blockIdx.x;
    __shared__ int cnt;
    if (threadIdx.x == 0) cnt = 0;
    __syncthreads();
    const int4* row = (const int4*)(mask + (size_t)i * N);
    for (int c = threadIdx.x; c < N / 4; c += 256) {
        int4 m4 = row[c];
        int base = 4 * c;
        if (m4.x) { int p = atomicAdd(&cnt, 1); if (p < CAP) nbr[(size_t)i * CAP + p] = (unsigned short)(base); }
        if (m4.y) { int p = atomicAdd(&cnt, 1); if (p < CAP) nbr[(size_t)i * CAP + p] = (unsigned short)(base + 1); }
        if (m4.z) { int p = atomicAdd(&cnt, 1); if (p < CAP) nbr[(size_t)i * CAP + p] = (unsigned short)(base + 2); }
        if (m4.w) { int p = atomicAdd(&cnt, 1); if (p < CAP) nbr[(size_t)i * CAP + p] = (unsigned short)(base + 3); }
    }
    __syncthreads();
    if (threadIdx.x == 0) deg[i] = (cnt > CAP) ? CAP : cnt;
}

// ---------------------------------------------------------------------------
// Fused Q/K/V projection (layer 0): A staged once, 3 GEMMs, f16 outputs.
// ---------------------------------------------------------------------------
__global__ __launch_bounds__(256) void qkv_gemm(const float* __restrict__ A,
                                                const float* __restrict__ Wq, const float* __restrict__ bq,
                                                const float* __restrict__ Wk, const float* __restrict__ bk,
                                                const float* __restrict__ Wv, const float* __restrict__ bv,
                                                __half* __restrict__ Qo, __half* __restrict__ Ko,
                                                __half* __restrict__ Vo) {
    __shared__ float As[8][D];
    const int tid = threadIdx.x;
    const int r   = tid >> 5;
    const int jg  = tid & 31;
    const int i0  = blockIdx.x * 8;

    ((float4*)&As[0][0])[tid] = ((const float4*)(A + (size_t)i0 * D))[tid];
    __syncthreads();

    const float* Ws[3] = {Wq, Wk, Wv};
    const float* bs[3] = {bq, bk, bv};
    __half* Os[3] = {Qo, Ko, Vo};

    #pragma unroll
    for (int m = 0; m < 3; ++m) {
        float4 acc = *(const float4*)(bs[m] + 4 * jg);
        const float* W = Ws[m];
        #pragma unroll 8
        for (int k4 = 0; k4 < 32; ++k4) {
            const float4 a4 = *(const float4*)&As[r][4 * k4];
            const float* wb = W + (size_t)(4 * k4) * D + 4 * jg;
            const float4 w0 = *(const float4*)(wb);
            const float4 w1 = *(const float4*)(wb + D);
            const float4 w2 = *(const float4*)(wb + 2 * D);
            const float4 w3 = *(const float4*)(wb + 3 * D);
            acc.x += a4.x * w0.x + a4.y * w1.x + a4.z * w2.x + a4.w * w3.x;
            acc.y += a4.x * w0.y + a4.y * w1.y + a4.z * w2.y + a4.w * w3.y;
            acc.z += a4.x * w0.z + a4.y * w1.z + a4.z * w2.z + a4.w * w3.z;
            acc.w += a4.x * w0.w + a4.y * w1.w + a4.z * w2.w + a4.w * w3.w;
        }
        f16x4 h;
        h[0] = (_Float16)acc.x; h[1] = (_Float16)acc.y;
        h[2] = (_Float16)acc.z; h[3] = (_Float16)acc.w;
        *(f16x4*)(Os[m] + (size_t)(i0 + r) * D + 4 * jg) = h;
    }
}

// ---------------------------------------------------------------------------
// Fused layer boundary: h = Aattn@Wo + bo (fp32 out to Hout) then Q/K/V of the
// NEXT layer from h (kept in LDS). Saves a dispatch + 4 MB h re-read.
// ---------------------------------------------------------------------------
__global__ __launch_bounds__(256) void gemmO_qkv(const float* __restrict__ Aattn,
                                                 const float* __restrict__ Wo, const float* __restrict__ bo,
                                                 float* __restrict__ Hout,
                                                 const float* __restrict__ Wq, const float* __restrict__ bq,
                                                 const float* __restrict__ Wk, const float* __restrict__ bk,
                                                 const float* __restrict__ Wv, const float* __restrict__ bv,
                                                 __half* __restrict__ Qo, __half* __restrict__ Ko,
                                                 __half* __restrict__ Vo) {
    __shared__ float As[8][D];
    __shared__ float Hs[8][D];
    const int tid = threadIdx.x;
    const int r   = tid >> 5;
    const int jg  = tid & 31;
    const int i0  = blockIdx.x * 8;

    ((float4*)&As[0][0])[tid] = ((const float4*)(Aattn + (size_t)i0 * D))[tid];
    __syncthreads();

    // h = As @ Wo + bo
    {
        float4 acc = *(const float4*)(bo + 4 * jg);
        #pragma unroll 8
        for (int k4 = 0; k4 < 32; ++k4) {
            const float4 a4 = *(const float4*)&As[r][4 * k4];
            const float* wb = Wo + (size_t)(4 * k4) * D + 4 * jg;
            const float4 w0 = *(const float4*)(wb);
            const float4 w1 = *(const float4*)(wb + D);
            const float4 w2 = *(const float4*)(wb + 2 * D);
            const float4 w3 = *(const float4*)(wb + 3 * D);
            acc.x += a4.x * w0.x + a4.y * w1.x + a4.z * w2.x + a4.w * w3.x;
            acc.y += a4.x * w0.y + a4.y * w1.y + a4.z * w2.y + a4.w * w3.y;
            acc.z += a4.x * w0.z + a4.y * w1.z + a4.z * w2.z + a4.w * w3.z;
            acc.w += a4.x * w0.w + a4.y * w1.w + a4.z * w2.w + a4.w * w3.w;
        }
        *(float4*)(Hout + (size_t)(i0 + r) * D + 4 * jg) = acc;
        *(float4*)&Hs[r][4 * jg] = acc;
    }
    __syncthreads();

    // Q/K/V of next layer from Hs
    const float* Ws[3] = {Wq, Wk, Wv};
    const float* bs[3] = {bq, bk, bv};
    __half* Os[3] = {Qo, Ko, Vo};
    #pragma unroll
    for (int m = 0; m < 3; ++m) {
        float4 acc = *(const float4*)(bs[m] + 4 * jg);
        const float* W = Ws[m];
        #pragma unroll 8
        for (int k4 = 0; k4 < 32; ++k4) {
            const float4 a4 = *(const float4*)&Hs[r][4 * k4];
            const float* wb = W + (size_t)(4 * k4) * D + 4 * jg;
            const float4 w0 = *(const float4*)(wb);
            const float4 w1 = *(const float4*)(wb + D);
            const float4 w2 = *(const float4*)(wb + 2 * D);
            const float4 w3 = *(const float4*)(wb + 3 * D);
            acc.x += a4.x * w0.x + a4.y * w1.x + a4.z * w2.x + a4.w * w3.x;
            acc.y += a4.x * w0.y + a4.y * w1.y + a4.z * w2.y + a4.w * w3.y;
            acc.z += a4.x * w0.z + a4.y * w1.z + a4.z * w2.z + a4.w * w3.z;
            acc.w += a4.x * w0.w + a4.y * w1.w + a4.z * w2.w + a4.w * w3.w;
        }
        f16x4 h;
        h[0] = (_Float16)acc.x; h[1] = (_Float16)acc.y;
        h[2] = (_Float16)acc.z; h[3] = (_Float16)acc.w;
        *(f16x4*)(Os[m] + (size_t)(i0 + r) * D + 4 * jg) = h;
    }
}

// ---------------------------------------------------------------------------
// Final output projection (fp32 in/out).
// ---------------------------------------------------------------------------
__global__ __launch_bounds__(256) void gemm_bias(const float* __restrict__ A,
                                                 const float* __restrict__ W,
                                                 const float* __restrict__ bias,
                                                 float* __restrict__ C) {
    __shared__ float As[8][D];
    const int tid = threadIdx.x;
    const int r   = tid >> 5;
    const int jg  = tid & 31;
    const int i0  = blockIdx.x * 8;

    ((float4*)&As[0][0])[tid] = ((const float4*)(A + (size_t)i0 * D))[tid];
    __syncthreads();

    float4 acc = *(const float4*)(bias + 4 * jg);
    #pragma unroll 8
    for (int k4 = 0; k4 < 32; ++k4) {
        const float4 a4 = *(const float4*)&As[r][4 * k4];
        const float* wb = W + (size_t)(4 * k4) * D + 4 * jg;
        const float4 w0 = *(const float4*)(wb);
        const float4 w1 = *(const float4*)(wb + D);
        const float4 w2 = *(const float4*)(wb + 2 * D);
        const float4 w3 = *(const float4*)(wb + 3 * D);
        acc.x += a4.x * w0.x + a4.y * w1.x + a4.z * w2.x + a4.w * w3.x;
        acc.y += a4.x * w0.y + a4.y * w1.y + a4.z * w2.y + a4.w * w3.y;
        acc.z += a4.x * w0.z + a4.y * w1.z + a4.z * w2.z + a4.w * w3.z;
        acc.w += a4.x * w0.w + a4.y * w1.w + a4.z * w2.w + a4.w * w3.w;
    }
    *(float4*)(C + (size_t)(i0 + r) * D + 4 * jg) = acc;
}

// ---------------------------------------------------------------------------
// Sparse masked attention, f16 Q/K/V. One block (256 thr) per query row.
// Phase 2: 16 lanes per neighbor — each K row read as contiguous 256 B
//          (4 cache lines vs 64 scattered in R3); Q fragment in registers;
//          4-step shfl_xor reduce within the 16-lane group.
// Phase 3: single-wave butterfly softmax.
// Phase 4: 16 lanes per V row, f16x8 loads, 8-float register acc,
//          LDS[16][128] combine.
// ---------------------------------------------------------------------------
__global__ __launch_bounds__(256) void attn_sparse(const __half* __restrict__ Q,
                                                   const __half* __restrict__ K,
                                                   const __half* __restrict__ V,
                                                   const unsigned short* __restrict__ nbr,
                                                   const int* __restrict__ deg,
                                                   float* __restrict__ Hout) {
    const int i    = blockIdx.x;
    const int tid  = threadIdx.x;
    const int wave = tid >> 6;
    const int lane = tid & 63;
    const int g    = lane >> 4;     // 16-lane group within wave (0..3)
    const int gl   = lane & 15;     // lane within group

    __shared__ float          s[CAP];
    __shared__ unsigned short jls[CAP];
    __shared__ float          red[16][D];   // 8 KB
    __shared__ float          inv_sh;

    const int dg = deg[i];
    for (int e = tid; e < dg; e += 256) jls[e] = nbr[(size_t)i * CAP + e];

    // loop-invariant Q fragment: lane gl holds Q[i][8*gl .. 8*gl+7]
    const f16x8 qv = ((const f16x8*)(Q + (size_t)i * D))[gl];
    __syncthreads();

    const float scale = 0.088388347648318447f;  // 1/sqrt(128)

    // phase 2: 16 lanes cooperate on one neighbor's dot product
    for (int e = wave * 4 + g; e < dg; e += 16) {
        const f16x8 kv = ((const f16x8*)(K + (size_t)jls[e] * D))[gl];
        float dot = dot8(kv, qv, 0.f);
        dot += __shfl_xor(dot, 1);
        dot += __shfl_xor(dot, 2);
        dot += __shfl_xor(dot, 4);
        dot += __shfl_xor(dot, 8);
        if (gl == 0) s[e] = dot * scale;
    }
    __syncthreads();

    // phase 3: softmax on wave 0 (butterfly over 64 lanes)
    if (wave == 0) {
        float lm = -1e30f;
        for (int e = lane; e < dg; e += 64) lm = fmaxf(lm, s[e]);
        #pragma unroll
        for (int off = 32; off > 0; off >>= 1)
            lm = fmaxf(lm, __shfl_xor(lm, off));
        float ls = 0.f;
        for (int e = lane; e < dg; e += 64) {
            const float p = __expf(s[e] - lm);
            s[e] = p;
            ls += p;
        }
        #pragma unroll
        for (int off = 32; off > 0; off >>= 1)
            ls += __shfl_xor(ls, off);
        if (lane == 0) inv_sh = 1.0f / ls;
    }
    __syncthreads();

    // phase 4: 16 lanes per V row; slice = tid>>4 handles e = slice, slice+16, ...
    const int slice = tid >> 4;
    float acc[8] = {0.f, 0.f, 0.f, 0.f, 0.f, 0.f, 0.f, 0.f};
    for (int e = slice; e < dg; e += 16) {
        const float p  = s[e];
        const f16x8 v8 = ((const f16x8*)(V + (size_t)jls[e] * D))[gl];
        #pragma unroll
        for (int k = 0; k < 8; ++k) acc[k] += p * (float)v8[k];
    }
    #pragma unroll
    for (int k = 0; k < 8; ++k) red[slice][8 * gl + k] = acc[k];
    __syncthreads();
    if (tid < D) {
        float sum = 0.f;
        #pragma unroll
        for (int sl = 0; sl < 16; ++sl) sum += red[sl][tid];
        Hout[(size_t)i * D + tid] = sum * inv_sh;
    }
}

__global__ __launch_bounds__(256) void copy_f4(const float4* __restrict__ in,
                                               float4* __restrict__ out, int n4) {
    int idx = blockIdx.x * 256 + threadIdx.x;
    if (idx < n4) out[idx] = in[idx];
}

extern "C" void kernel_launch(void* const* d_in, const int* in_sizes, int n_in,
                              void* d_out, int out_size, void* d_ws, size_t ws_size,
                              hipStream_t stream) {
    const float* features = (const float*)d_in[0];
    const int*   mask     = (const int*)d_in[1];
    const float* Wq = (const float*)d_in[2];
    const float* bq = (const float*)d_in[3];
    const float* Wk = (const float*)d_in[4];
    const float* bk = (const float*)d_in[5];
    const float* Wv = (const float*)d_in[6];
    const float* bv = (const float*)d_in[7];
    const float* Wo = (const float*)d_in[8];
    const float* bo = (const float*)d_in[9];
    float* out = (float*)d_out;

    // workspace layout (~18.5 MB)
    char* base = (char*)d_ws;
    unsigned short* nbr = (unsigned short*)base;                        // 8 MB
    int*    deg  = (int*)(base + (size_t)N * CAP * 2);                  // 32 KB
    __half* Qb16 = (__half*)(base + (size_t)N * CAP * 2 + N * 4);       // 2 MB
    __half* Kb16 = Qb16 + (size_t)N * D;                                // 2 MB
    __half* Vb16 = Kb16 + (size_t)N * D;                                // 2 MB
    float*  tmp  = (float*)(Vb16 + (size_t)N * D);                      // 4 MB

    build_adj<<<N, 256, 0, stream>>>(mask, nbr, deg);

    copy_f4<<<(N * D / 4 + 255) / 256, 256, 0, stream>>>(
        (const float4*)features, (float4*)out, N * D / 4);

    // layer 0 QKV
    qkv_gemm<<<N / 8, 256, 0, stream>>>(features, Wq, bq, Wk, bk, Wv, bv,
                                        Qb16, Kb16, Vb16);
    // layer 0 attention
    attn_sparse<<<N, 256, 0, stream>>>(Qb16, Kb16, Vb16, nbr, deg, tmp);
    // layer 0 output proj + layer 1 QKV (fused)
    gemmO_qkv<<<N / 8, 256, 0, stream>>>(tmp, Wo, bo, out + (size_t)N * D,
                                         Wq + D * D, bq + D, Wk + D * D, bk + D,
                                         Wv + D * D, bv + D, Qb16, Kb16, Vb16);
    // layer 1 attention
    attn_sparse<<<N, 256, 0, stream>>>(Qb16, Kb16, Vb16, nbr, deg, tmp);
    // layer 1 output proj
    gemm_bias<<<N / 8, 256, 0, stream>>>(tmp, Wo + D * D, bo + D,
                                         out + (size_t)2 * N * D);
}